// Round 2
// baseline (5352.709 us; speedup 1.0000x reference)
//
#include <hip/hip_runtime.h>
#include <math.h>

typedef long long ll;

#define NBATCH 4
#define TSEQ   4095
#define NTOK   4096
#define DMODEL 512
#define NHEAD  8
#define DHEAD  64
#define NLAND  256
#define INDIM  1024
#define KCONV  33
#define NBH    32   // NBATCH*NHEAD

// ---------------- block reduce helper (256 threads) ----------------
__device__ __forceinline__ float bred(float* red, float v, int tid, int op /*0=sum,1=max*/){
  red[tid] = v; __syncthreads();
  for (int s = 128; s > 0; s >>= 1){
    if (tid < s) red[tid] = op ? fmaxf(red[tid], red[tid+s]) : (red[tid] + red[tid+s]);
    __syncthreads();
  }
  float r = red[0];
  __syncthreads();
  return r;
}

// ---------------- PE table (float64 like numpy) ----------------
__global__ __launch_bounds__(256) void pe_table_k(float* __restrict__ pe){
  int idx = blockIdx.x*256 + threadIdx.x;
  if (idx >= TSEQ*DMODEL) return;
  int c = idx & 511; int t = idx >> 9;
  const double NEG = -9.210340371976184 / 512.0;  // -ln(10000)/512
  double div = exp((double)(c & ~1) * NEG);
  double ang = (double)t * div;
  pe[idx] = (c & 1) ? (float)cos(ang) : (float)sin(ang);
}

// h[b,0,:] = cls ; h[b,1+t,:] += pe[t,:]
__global__ __launch_bounds__(256) void pe_cls_add_k(float* __restrict__ hb, const float* __restrict__ cls,
                                                    const float* __restrict__ pe){
  ll idx = (ll)blockIdx.x*256 + threadIdx.x;   // < NBATCH*NTOK*DMODEL
  int c = (int)(idx & 511);
  ll rn = idx >> 9;
  int n = (int)(rn & 4095);
  if (n == 0) hb[idx] = cls[c];
  else        hb[idx] += pe[(ll)(n-1)*512 + c];
}

// ---------------- LayerNorm rows (D=512) ----------------
__global__ __launch_bounds__(256) void ln_rows_k(const float* __restrict__ in, float* __restrict__ out,
                                                 const float* __restrict__ sc, const float* __restrict__ bi){
  __shared__ float red[256];
  ll row = blockIdx.x;
  const float* xr = in + row*DMODEL;
  float* orow = out + row*DMODEL;
  int tid = threadIdx.x;
  float v0 = xr[tid], v1 = xr[tid+256];
  float mu = bred(red, v0+v1, tid, 0) * (1.f/512.f);
  float d0 = v0-mu, d1 = v1-mu;
  float var = bred(red, d0*d0 + d1*d1, tid, 0) * (1.f/512.f);
  float inv = 1.f / sqrtf(var + 1e-5f);
  orow[tid]     = d0*inv*sc[tid]     + bi[tid];
  orow[tid+256] = d1*inv*sc[tid+256] + bi[tid+256];
}

// ---------------- generic NN GEMM: C = A(MxK) @ B(KxN), 64x64 tile ----------------
// flags: 1=+bias[n]  2=relu  4=C=c0*E+c1*acc  8=+=C(old residual)  16=fc1 row remap
__global__ __launch_bounds__(256)
void gemm_nn(const float* __restrict__ A, const float* __restrict__ Bm,
             float* __restrict__ C, const float* __restrict__ E,
             const float* __restrict__ bias,
             int Mr, int K, int lda, int ldb, int ldc,
             ll sAb, ll sAh, ll sBb, ll sBh, ll sCb, ll sCh,
             float c0, float c1, int flags)
{
  __shared__ float As[16][66];
  __shared__ float Bs[16][64];
  int z = blockIdx.z; int b = z >> 3; int h = z & 7;
  A  += (ll)b*sAb + (ll)h*sAh;
  Bm += (ll)b*sBb + (ll)h*sBh;
  C  += (ll)b*sCb + (ll)h*sCh;
  if (E) E += (ll)b*sCb + (ll)h*sCh;
  int n0 = blockIdx.x*64, m0 = blockIdx.y*64;
  int tid = threadIdx.x;
  int tx = tid & 15, ty = tid >> 4;
  float acc[4][4] = {};
  int ka = tid & 15, ra = tid >> 4;
  int nb = tid & 63, kb = tid >> 6;
  for (int k0 = 0; k0 < K; k0 += 16){
    #pragma unroll
    for (int r = 0; r < 4; r++){
      int row = m0 + ra + 16*r;
      As[ka][ra + 16*r] = (row < Mr) ? A[(ll)row*lda + k0 + ka] : 0.f;
    }
    #pragma unroll
    for (int r = 0; r < 4; r++)
      Bs[kb + 4*r][nb] = Bm[(ll)(k0 + kb + 4*r)*ldb + n0 + nb];
    __syncthreads();
    #pragma unroll
    for (int k = 0; k < 16; k++){
      float a[4], bv[4];
      #pragma unroll
      for (int i = 0; i < 4; i++) a[i] = As[k][ty + 16*i];
      #pragma unroll
      for (int j = 0; j < 4; j++) bv[j] = Bs[k][tx + 16*j];
      #pragma unroll
      for (int i = 0; i < 4; i++)
        #pragma unroll
        for (int j = 0; j < 4; j++)
          acc[i][j] += a[i]*bv[j];
    }
    __syncthreads();
  }
  #pragma unroll
  for (int i = 0; i < 4; i++){
    int m = m0 + ty + 16*i;
    if (m >= Mr) continue;
    int om = (flags & 16) ? (m + m/TSEQ + 1) : m;
    #pragma unroll
    for (int j = 0; j < 4; j++){
      int n = n0 + tx + 16*j;
      float v = acc[i][j];
      if (flags & 4) v = c0 * E[(ll)m*ldc + n] + c1 * v;
      if (flags & 1) v += bias[n];
      if (flags & 2) v = fmaxf(v, 0.f);
      ll ci = (ll)om*ldc + n;
      if (flags & 8) v += C[ci];
      C[ci] = v;
    }
  }
}

// ---------------- NT GEMM (K fixed = 64, used for attn2 scores only) ----------------
__global__ __launch_bounds__(256)
void gemm_nt(const float* __restrict__ A, const float* __restrict__ Bm, float* __restrict__ C,
             int lda, int ldb, int ldc,
             ll sAb, ll sAh, ll sBb, ll sBh, ll sCb, ll sCh,
             float alpha)
{
  __shared__ float As[64][65];
  __shared__ float Bs[64][65];
  int z = blockIdx.z; int b = z >> 3; int h = z & 7;
  A  += (ll)b*sAb + (ll)h*sAh;
  Bm += (ll)b*sBb + (ll)h*sBh;
  C  += (ll)b*sCb + (ll)h*sCh;
  int n0 = blockIdx.x*64, m0 = blockIdx.y*64;
  int tid = threadIdx.x;
  int kk = tid & 63, rr = tid >> 6;
  #pragma unroll
  for (int r = 0; r < 16; r++){
    As[rr + 4*r][kk] = A [(ll)(m0 + rr + 4*r)*lda + kk];
    Bs[rr + 4*r][kk] = Bm[(ll)(n0 + rr + 4*r)*ldb + kk];
  }
  __syncthreads();
  int tx = tid & 15, ty = tid >> 4;
  float acc[4][4] = {};
  for (int k = 0; k < 64; k++){
    float a[4], bv[4];
    #pragma unroll
    for (int i = 0; i < 4; i++) a[i] = As[ty + 16*i][k];
    #pragma unroll
    for (int j = 0; j < 4; j++) bv[j] = Bs[tx + 16*j][k];
    #pragma unroll
    for (int i = 0; i < 4; i++)
      #pragma unroll
      for (int j = 0; j < 4; j++)
        acc[i][j] += a[i]*bv[j];
  }
  #pragma unroll
  for (int i = 0; i < 4; i++)
    #pragma unroll
    for (int j = 0; j < 4; j++)
      C[(ll)(m0 + ty + 16*i)*ldc + n0 + tx + 16*j] = alpha * acc[i][j];
}

// ---------------- fused flash attention: O = softmax(alpha * Q @ K^T) @ V --------
// 64 query rows per block; K/V chunked by 64; online softmax; dh = 64 fixed.
__global__ __launch_bounds__(256)
void flash_k(const float* __restrict__ Q, const float* __restrict__ K,
             const float* __restrict__ V, float* __restrict__ O,
             int ldq, int ldk, int ldv, int ldo, int nkeys, float alpha,
             ll sQb, ll sQh, ll sKb, ll sKh, ll sVb, ll sVh, ll sOb, ll sOh)
{
  __shared__ float qs[64][65];
  __shared__ float kv[64][65];
  __shared__ float ps[64][65];
  int z = blockIdx.z; int b = z >> 3; int h = z & 7;
  Q += (ll)b*sQb + (ll)h*sQh;
  K += (ll)b*sKb + (ll)h*sKh;
  V += (ll)b*sVb + (ll)h*sVh;
  O += (ll)b*sOb + (ll)h*sOh;
  int m0 = blockIdx.x * 64;
  int tid = threadIdx.x;
  int kk = tid & 63, rr = tid >> 6;
  #pragma unroll
  for (int r = 0; r < 16; r++)
    qs[rr + 4*r][kk] = Q[(ll)(m0 + rr + 4*r)*ldq + kk] * alpha;
  int tx = tid & 15, ty = tid >> 4;
  float o[4][4] = {};
  float mrow[4], ssum[4];
  #pragma unroll
  for (int i = 0; i < 4; i++){ mrow[i] = -1e30f; ssum[i] = 0.f; }

  for (int n0 = 0; n0 < nkeys; n0 += 64){
    __syncthreads();   // prev PV done (and qs ready on first iter)
    #pragma unroll
    for (int r = 0; r < 16; r++)
      kv[rr + 4*r][kk] = K[(ll)(n0 + rr + 4*r)*ldk + kk];
    __syncthreads();
    float s[4][4] = {};
    for (int d = 0; d < 64; d++){
      float a[4], bv[4];
      #pragma unroll
      for (int i = 0; i < 4; i++) a[i] = qs[ty + 16*i][d];
      #pragma unroll
      for (int j = 0; j < 4; j++) bv[j] = kv[tx + 16*j][d];
      #pragma unroll
      for (int i = 0; i < 4; i++)
        #pragma unroll
        for (int j = 0; j < 4; j++) s[i][j] += a[i]*bv[j];
    }
    #pragma unroll
    for (int i = 0; i < 4; i++){
      float cm = fmaxf(fmaxf(s[i][0], s[i][1]), fmaxf(s[i][2], s[i][3]));
      #pragma unroll
      for (int off = 1; off < 16; off <<= 1) cm = fmaxf(cm, __shfl_xor(cm, off));
      float mn = fmaxf(mrow[i], cm);
      float scale = expf(mrow[i] - mn);
      mrow[i] = mn;
      float psum = 0.f;
      #pragma unroll
      for (int j = 0; j < 4; j++){ s[i][j] = expf(s[i][j] - mn); psum += s[i][j]; }
      #pragma unroll
      for (int off = 1; off < 16; off <<= 1) psum += __shfl_xor(psum, off);
      ssum[i] = ssum[i]*scale + psum;
      #pragma unroll
      for (int j = 0; j < 4; j++){
        o[i][j] *= scale;
        ps[ty + 16*i][tx + 16*j] = s[i][j];
      }
    }
    __syncthreads();   // ps ready, kv free
    #pragma unroll
    for (int r = 0; r < 16; r++)
      kv[rr + 4*r][kk] = V[(ll)(n0 + rr + 4*r)*ldv + kk];
    __syncthreads();
    for (int kx = 0; kx < 64; kx++){
      float a[4], bv[4];
      #pragma unroll
      for (int i = 0; i < 4; i++) a[i] = ps[ty + 16*i][kx];
      #pragma unroll
      for (int j = 0; j < 4; j++) bv[j] = kv[kx][tx + 16*j];
      #pragma unroll
      for (int i = 0; i < 4; i++)
        #pragma unroll
        for (int j = 0; j < 4; j++) o[i][j] += a[i]*bv[j];
    }
  }
  #pragma unroll
  for (int i = 0; i < 4; i++){
    float inv = 1.f / ssum[i];
    #pragma unroll
    for (int j = 0; j < 4; j++)
      O[(ll)(m0 + ty + 16*i)*ldo + tx + 16*j] = o[i][j] * inv;
  }
}

// ---------------- row softmax (in place, a2 only) ----------------
__global__ __launch_bounds__(256) void softmax_rows_k(float* __restrict__ data, int cols){
  __shared__ float red[256];
  float* row = data + (ll)blockIdx.x * cols;
  int tid = threadIdx.x;
  float m = -1e30f;
  for (int c = tid; c < cols; c += 256) m = fmaxf(m, row[c]);
  m = bred(red, m, tid, 1);
  float s = 0.f;
  for (int c = tid; c < cols; c += 256){ float e = expf(row[c] - m); row[c] = e; s += e; }
  s = bred(red, s, tid, 0);
  float inv = 1.f/s;
  for (int c = tid; c < cols; c += 256) row[c] *= inv;
}

// ---------------- landmark means (q scaled by 1/8) ----------------
__global__ __launch_bounds__(256) void landmarks_k(const float* __restrict__ qkv,
                                                   float* __restrict__ ql, float* __restrict__ kl){
  int idx = blockIdx.x*256 + threadIdx.x;   // < NBH*NLAND*DHEAD = 524288
  int d = idx & 63;
  int i = (idx >> 6) & 255;
  int h = (idx >> 14) & 7;
  int b = idx >> 17;
  const float* base = qkv + ((ll)b*NTOK + (ll)i*16)*1536 + h*64 + d;
  float sq = 0.f, sk = 0.f;
  #pragma unroll
  for (int l = 0; l < 16; l++){ sq += base[l*1536]; sk += base[l*1536 + 512]; }
  ql[idx] = sq * (0.125f/16.f);
  kl[idx] = sk * (1.f/16.f);
}

// ---------------- pinv denom: max row-sum & max col-sum of attn2 ----------------
__global__ void init_scal_k(unsigned* s){ s[0] = 0u; s[1] = 0u; }

__global__ __launch_bounds__(256) void a2_maxsums_k(const float* __restrict__ a2, unsigned* __restrict__ gm){
  __shared__ float red[256];
  const float* A = a2 + (ll)blockIdx.x*65536;
  int tid = threadIdx.x;
  float cs = 0.f, rs = 0.f;
  for (int i = 0; i < 256; i++) cs += A[i*256 + tid];
  for (int j = 0; j < 256; j++) rs += A[tid*256 + j];
  float cmax = bred(red, cs, tid, 1);
  float rmax = bred(red, rs, tid, 1);
  if (tid == 0){
    atomicMax(gm + 0, __float_as_uint(rmax));  // ax.sum(-1).max()
    atomicMax(gm + 1, __float_as_uint(cmax));  // ax.sum(-2).max()
  }
}

// z0 = attn2^T / denom
__global__ __launch_bounds__(256) void zinit_k(const float* __restrict__ a2, float* __restrict__ z,
                                               const unsigned* __restrict__ gm){
  float inv = 1.f / (__uint_as_float(gm[0]) * __uint_as_float(gm[1]));
  int idx = blockIdx.x*256 + threadIdx.x;   // < 2097152
  int j = idx & 255, i = (idx >> 8) & 255, bh = idx >> 16;
  z[idx] = a2[(ll)bh*65536 + j*256 + i] * inv;
}

// ---------------- depthwise conv over sequence, += into out ----------------
__global__ __launch_bounds__(256) void dwconv_add_k(const float* __restrict__ qkv,
                                                    const float* __restrict__ cw, float* __restrict__ out){
  __shared__ float sv[160][64];
  __shared__ float w[KCONV];
  int z = blockIdx.y; int b = z >> 3; int h = z & 7;
  int t0 = blockIdx.x * 128;
  int tid = threadIdx.x;
  if (tid < KCONV) w[tid] = cw[h*KCONV + tid];
  const float* vbase = qkv + (ll)b*NTOK*1536 + 1024 + h*64;
  for (int e = tid; e < 160*64; e += 256){
    int r = e >> 6, d = e & 63;
    int t = t0 - 16 + r;
    sv[r][d] = (t >= 0 && t < NTOK) ? vbase[(ll)t*1536 + d] : 0.f;
  }
  __syncthreads();
  float* obase = out + (ll)b*NTOK*512 + h*64;
  for (int e = tid; e < 128*64; e += 256){
    int r = e >> 6, d = e & 63;
    float s = 0.f;
    #pragma unroll
    for (int kk = 0; kk < KCONV; kk++) s += sv[r+kk][d]*w[kk];
    obase[(ll)(t0+r)*512 + d] += s;
  }
}

// ---------------- final head: LN(h[b,0]) . fcout + sigmoid ----------------
__global__ __launch_bounds__(256) void head_k(const float* __restrict__ hb, const float* __restrict__ fns,
      const float* __restrict__ fnb, const float* __restrict__ fw, const float* __restrict__ fb,
      float* __restrict__ out){
  __shared__ float red[256];
  int b = blockIdx.x;
  const float* xr = hb + (ll)b*NTOK*DMODEL;
  int tid = threadIdx.x;
  float v0 = xr[tid], v1 = xr[tid+256];
  float mu = bred(red, v0+v1, tid, 0) * (1.f/512.f);
  float d0 = v0-mu, d1 = v1-mu;
  float var = bred(red, d0*d0 + d1*d1, tid, 0) * (1.f/512.f);
  float inv = 1.f/sqrtf(var + 1e-5f);
  float y0 = d0*inv*fns[tid]     + fnb[tid];
  float y1 = d1*inv*fns[tid+256] + fnb[tid+256];
  float dot = bred(red, y0*fw[tid] + y1*fw[tid+256], tid, 0);
  if (tid == 0){
    float logit = dot + fb[0];
    float prob = 1.f/(1.f + expf(-logit));
    out[b] = logit; out[4+b] = prob; out[8+b] = (prob > 0.5f) ? 1.f : 0.f;
  }
}

// =============================================================================
extern "C" void kernel_launch(void* const* d_in, const int* in_sizes, int n_in,
                              void* d_out, int out_size, void* d_ws, size_t ws_size,
                              hipStream_t stream)
{
  (void)in_sizes; (void)n_in; (void)out_size;
  const float* data  = (const float*)d_in[0];
  const float* fc1_w = (const float*)d_in[1];
  const float* fc1_b = (const float*)d_in[2];
  const float* cls   = (const float*)d_in[3];
  const float* ln_s  = (const float*)d_in[4];
  const float* ln_b  = (const float*)d_in[5];
  const float* qkv_w = (const float*)d_in[6];
  const float* out_w = (const float*)d_in[7];
  const float* out_b = (const float*)d_in[8];
  const float* convw = (const float*)d_in[9];
  const float* fns   = (const float*)d_in[10];
  const float* fnb   = (const float*)d_in[11];
  const float* fcw   = (const float*)d_in[12];
  const float* fcb   = (const float*)d_in[13];
  float* out = (float*)d_out;
  float* ws  = (float*)d_ws;

  // workspace layout (floats)
  float* h   = ws;                   //  8,388,608
  float* x   = h   + 8388608;        //  8,388,608
  float* qkv = x   + 8388608;        // 25,165,824
  float* ql  = qkv + 25165824;       //    524,288
  float* kl  = ql  + 524288;         //    524,288
  float* a2  = kl  + 524288;         //  2,097,152
  float* zA  = a2  + 2097152;        //  2,097,152
  float* zB  = zA  + 2097152;        //  2,097,152
  float* t1  = zB  + 2097152;        //  2,097,152 (PE table aliased here pre-loop)
  float* t2  = t1  + 2097152;        //  2,097,152
  float* t3  = t2  + 2097152;        //  2,097,152
  float* av  = t3  + 2097152;        //    524,288
  float* y2  = av  + 524288;         //    524,288
  unsigned* scal = (unsigned*)(y2 + 524288);
  float* pe = t1;                    // alias: PE dead before pinv loop starts

  const size_t NEED = (size_t)(56623104 + 16) * sizeof(float);  // ~226.5 MB
  if (ws_size < NEED) return;  // diagnostic guard: clean fail instead of fault

  // --- PE table + fc1 GEMM (bias,relu, row remap to h[b,1+t]) + cls/PE add ---
  pe_table_k<<<(TSEQ*DMODEL + 255)/256, 256, 0, stream>>>(pe);
  gemm_nn<<<dim3(8, 256, 1), 256, 0, stream>>>(
      data, fc1_w, h, nullptr, fc1_b,
      NBATCH*TSEQ, INDIM, INDIM, DMODEL, DMODEL,
      0,0, 0,0, 0,0, 0.f, 0.f, /*bias|relu|remap*/ 1|2|16);
  pe_cls_add_k<<<(NBATCH*NTOK*DMODEL)/256, 256, 0, stream>>>(h, cls, pe);

  for (int L = 0; L < 2; L++){
    const float* qw = qkv_w + (ll)L*DMODEL*1536;
    const float* ow = out_w + (ll)L*DMODEL*DMODEL;
    const float* ob = out_b + (ll)L*DMODEL;
    const float* cw = convw + (ll)L*NHEAD*KCONV;

    ln_rows_k<<<NBATCH*NTOK, 256, 0, stream>>>(h, x, ln_s + L*DMODEL, ln_b + L*DMODEL);
    gemm_nn<<<dim3(24, 256, 1), 256, 0, stream>>>(
        x, qw, qkv, nullptr, nullptr,
        NBATCH*NTOK, DMODEL, DMODEL, 1536, 1536,
        0,0, 0,0, 0,0, 0.f, 0.f, 0);
    landmarks_k<<<2048, 256, 0, stream>>>(qkv, ql, kl);

    // attn2 = softmax(ql @ kl^T)   [b,h,256,256]
    gemm_nt<<<dim3(4, 4, NBH), 256, 0, stream>>>(
        ql, kl, a2, 64, 64, 256,
        131072, 16384, 131072, 16384, 524288, 65536, 1.f);
    softmax_rows_k<<<NBH*NLAND, 256, 0, stream>>>(a2, 256);

    // pinv init
    init_scal_k<<<1, 1, 0, stream>>>(scal);
    a2_maxsums_k<<<NBH, 256, 0, stream>>>(a2, scal);
    zinit_k<<<8192, 256, 0, stream>>>(a2, zA, scal);

    // Newton-Schulz x6
    float* zc = zA; float* zn = zB;
    for (int it = 0; it < 6; it++){
      gemm_nn<<<dim3(4, 4, NBH), 256, 0, stream>>>(              // t1 = a2@z
          a2, zc, t1, nullptr, nullptr, 256, 256, 256, 256, 256,
          524288,65536, 524288,65536, 524288,65536, 0.f, 0.f, 0);
      gemm_nn<<<dim3(4, 4, NBH), 256, 0, stream>>>(              // t2 = 7t1 - t1@t1
          t1, t1, t2, t1, nullptr, 256, 256, 256, 256, 256,
          524288,65536, 524288,65536, 524288,65536, 7.f, -1.f, 4);
      gemm_nn<<<dim3(4, 4, NBH), 256, 0, stream>>>(              // t3 = 15t1 - t1@t2
          t1, t2, t3, t1, nullptr, 256, 256, 256, 256, 256,
          524288,65536, 524288,65536, 524288,65536, 15.f, -1.f, 4);
      gemm_nn<<<dim3(4, 4, NBH), 256, 0, stream>>>(              // zn = 3.25z - 0.25 z@t3
          zc, t3, zn, zc, nullptr, 256, 256, 256, 256, 256,
          524288,65536, 524288,65536, 524288,65536, 3.25f, -0.25f, 4);
      float* tmp = zc; zc = zn; zn = tmp;
    }

    // av = softmax(ql @ k^T) @ v      (fused flash, 4 q-blocks x 32 bh)
    flash_k<<<dim3(4, 1, NBH), 256, 0, stream>>>(
        ql, qkv + 512, qkv + 1024, av,
        64, 1536, 1536, 64, NTOK, 1.f,
        131072, 16384, (ll)NTOK*1536, 64, (ll)NTOK*1536, 64, 131072, 16384);

    // y2 = pinv @ av
    gemm_nn<<<dim3(1, 4, NBH), 256, 0, stream>>>(
        zc, av, y2, nullptr, nullptr, 256, 256, 256, 64, 64,
        524288,65536, 131072,16384, 131072,16384, 0.f, 0.f, 0);

    // x = softmax(0.125 q @ kl^T) @ y2    (fused flash, 64 q-blocks x 32 bh)
    flash_k<<<dim3(64, 1, NBH), 256, 0, stream>>>(
        qkv, kl, y2, x,
        1536, 64, 64, 512, NLAND, 0.125f,
        (ll)NTOK*1536, 64, 131072, 16384, 131072, 16384, (ll)NTOK*512, 64);

    // x += depthwise_conv(v)
    dwconv_add_k<<<dim3(32, NBH), 256, 0, stream>>>(qkv, cw, x);

    // h = h + x @ out_w + out_b
    gemm_nn<<<dim3(8, 256, 1), 256, 0, stream>>>(
        x, ow, h, nullptr, ob,
        NBATCH*NTOK, DMODEL, DMODEL, DMODEL, DMODEL,
        0,0, 0,0, 0,0, 0.f, 0.f, /*bias|residual*/ 1|8);
  }

  head_k<<<4, 256, 0, stream>>>(h, fns, fnb, fcw, fcb, out);
}

// Round 3
// 2098.450 us; speedup vs baseline: 2.5508x; 2.5508x over previous
//
#include <hip/hip_runtime.h>
#include <math.h>

typedef long long ll;
typedef __attribute__((ext_vector_type(8))) short short8;
typedef __attribute__((ext_vector_type(4))) float f32x4;

#define NBATCH 4
#define TSEQ   4095
#define NTOK   4096
#define DMODEL 512
#define NHEAD  8
#define DHEAD  64
#define NLAND  256
#define INDIM  1024
#define KCONV  33
#define NBH    32
#define NSPLIT 8

// ---------------- helpers ----------------
__device__ __forceinline__ float bred(float* red, float v, int tid, int op){
  red[tid] = v; __syncthreads();
  for (int s = 128; s > 0; s >>= 1){
    if (tid < s) red[tid] = op ? fmaxf(red[tid], red[tid+s]) : (red[tid] + red[tid+s]);
    __syncthreads();
  }
  float r = red[0];
  __syncthreads();
  return r;
}

__device__ __forceinline__ short f2bf(float f){  // RNE f32->bf16
  unsigned u = __float_as_uint(f);
  u += 0x7fff + ((u>>16)&1);
  return (short)(u>>16);
}

// ---------------- PE table (float64 like numpy) ----------------
__global__ __launch_bounds__(256) void pe_table_k(float* __restrict__ pe){
  int idx = blockIdx.x*256 + threadIdx.x;
  if (idx >= TSEQ*DMODEL) return;
  int c = idx & 511; int t = idx >> 9;
  const double NEG = -9.210340371976184 / 512.0;
  double div = exp((double)(c & ~1) * NEG);
  double ang = (double)t * div;
  pe[idx] = (c & 1) ? (float)cos(ang) : (float)sin(ang);
}

__global__ __launch_bounds__(256) void pe_cls_add_k(float* __restrict__ hb, const float* __restrict__ cls,
                                                    const float* __restrict__ pe){
  ll idx = (ll)blockIdx.x*256 + threadIdx.x;
  int c = (int)(idx & 511);
  ll rn = idx >> 9;
  int n = (int)(rn & 4095);
  if (n == 0) hb[idx] = cls[c];
  else        hb[idx] += pe[(ll)(n-1)*512 + c];
}

// ---------------- LayerNorm rows (D=512) ----------------
__global__ __launch_bounds__(256) void ln_rows_k(const float* __restrict__ in, float* __restrict__ out,
                                                 const float* __restrict__ sc, const float* __restrict__ bi){
  __shared__ float red[256];
  ll row = blockIdx.x;
  const float* xr = in + row*DMODEL;
  float* orow = out + row*DMODEL;
  int tid = threadIdx.x;
  float v0 = xr[tid], v1 = xr[tid+256];
  float mu = bred(red, v0+v1, tid, 0) * (1.f/512.f);
  float d0 = v0-mu, d1 = v1-mu;
  float var = bred(red, d0*d0 + d1*d1, tid, 0) * (1.f/512.f);
  float inv = 1.f / sqrtf(var + 1e-5f);
  orow[tid]     = d0*inv*sc[tid]     + bi[tid];
  orow[tid+256] = d1*inv*sc[tid+256] + bi[tid+256];
}

// ============ bf16 MFMA GEMM: C = A(MxK fp32) @ B(KxN fp32), fp32 out ============
// 256 thr = 4 waves (2x2), wave computes (BM/2)x(BN/2). BK=64, XOR-swizzled LDS.
// flags: 1=+bias[n]  2=relu  4=C=c0*E+c1*acc  8=+=C residual  16=fc1 row remap
template<int BM, int BN>
__global__ __launch_bounds__(256)
void mgemm(const float* __restrict__ A, const float* __restrict__ Bm,
           float* __restrict__ C, const float* __restrict__ E,
           const float* __restrict__ bias,
           int Mr, int K, int lda, int ldb, int ldc,
           ll sA, ll sB, ll sC,
           float c0, float c1, int flags)
{
  constexpr int MI = BM/32, NJ = BN/32;
  __shared__ __align__(16) short As[BM*64];
  __shared__ __align__(16) short Bs[BN*64];
  int z = blockIdx.z;
  A += (ll)z*sA; Bm += (ll)z*sB; C += (ll)z*sC;
  if (E) E += (ll)z*sC;
  int n0 = blockIdx.x*BN, m0 = blockIdx.y*BM;
  int tid = threadIdx.x;
  int lane = tid & 63, w = tid >> 6;
  int wr = w >> 1, wc = w & 1;
  int l15 = lane & 15, l4 = lane >> 4;

  f32x4 acc[MI][NJ];
  #pragma unroll
  for (int i = 0; i < MI; i++)
    #pragma unroll
    for (int j = 0; j < NJ; j++) acc[i][j] = (f32x4){0.f,0.f,0.f,0.f};

  for (int k0 = 0; k0 < K; k0 += 64){
    // stage A tile [BM][64] -> bf16, slot-swizzled
    #pragma unroll
    for (int it = 0; it < BM/32; ++it){
      int tau = tid + 256*it;
      int row = tau >> 3, slot = tau & 7;
      int grow = m0 + row;
      f32x4 p0 = {0.f,0.f,0.f,0.f}, p1 = {0.f,0.f,0.f,0.f};
      if (grow < Mr){
        const float* ap = A + (ll)grow*lda + k0 + slot*8;
        p0 = *(const f32x4*)ap; p1 = *(const f32x4*)(ap+4);
      }
      short8 v;
      v[0]=f2bf(p0[0]); v[1]=f2bf(p0[1]); v[2]=f2bf(p0[2]); v[3]=f2bf(p0[3]);
      v[4]=f2bf(p1[0]); v[5]=f2bf(p1[1]); v[6]=f2bf(p1[2]); v[7]=f2bf(p1[3]);
      ((short8*)As)[row*8 + (slot ^ (row&7))] = v;
    }
    // stage B tile transposed: Bs[n][k] <- B[k][n0+n]
    #pragma unroll
    for (int it = 0; it < BN/32; ++it){
      int tau = tid + 256*it;
      int n = tau & (BN-1), slot = tau >> (BN==128 ? 7 : 6);
      const float* bp = Bm + (ll)(k0 + slot*8)*ldb + n0 + n;
      short8 v;
      #pragma unroll
      for (int i = 0; i < 8; i++) v[i] = f2bf(bp[(ll)i*ldb]);
      ((short8*)Bs)[n*8 + (slot ^ (n&7))] = v;
    }
    __syncthreads();
    #pragma unroll
    for (int kc = 0; kc < 2; kc++){
      short8 af[MI], bf[NJ];
      #pragma unroll
      for (int i = 0; i < MI; i++){
        int row = wr*(BM/2) + i*16 + l15;
        int g = kc*4 + l4;
        af[i] = ((short8*)As)[row*8 + (g ^ (row&7))];
      }
      #pragma unroll
      for (int j = 0; j < NJ; j++){
        int col = wc*(BN/2) + j*16 + l15;
        int g = kc*4 + l4;
        bf[j] = ((short8*)Bs)[col*8 + (g ^ (col&7))];
      }
      #pragma unroll
      for (int i = 0; i < MI; i++)
        #pragma unroll
        for (int j = 0; j < NJ; j++)
          acc[i][j] = __builtin_amdgcn_mfma_f32_16x16x32_bf16(af[i], bf[j], acc[i][j], 0, 0, 0);
    }
    __syncthreads();
  }

  // epilogue: C/D frag layout col=lane&15, row=(lane>>4)*4+reg
  #pragma unroll
  for (int i = 0; i < MI; i++){
    int rbase = m0 + wr*(BM/2) + i*16 + l4*4;
    #pragma unroll
    for (int j = 0; j < NJ; j++){
      int col = n0 + wc*(BN/2) + j*16 + l15;
      #pragma unroll
      for (int r = 0; r < 4; r++){
        int m = rbase + r;
        if (m >= Mr) continue;
        float v = acc[i][j][r];
        if (flags & 4) v = c0 * E[(ll)m*ldc + col] + c1 * v;
        if (flags & 1) v += bias[col];
        if (flags & 2) v = fmaxf(v, 0.f);
        int om = (flags & 16) ? (m + m/TSEQ + 1) : m;
        ll ci = (ll)om*ldc + col;
        if (flags & 8) v += C[ci];
        C[ci] = v;
      }
    }
  }
}

// ---------------- NT GEMM fp32 (attn2 scores only, K=64) ----------------
__global__ __launch_bounds__(256)
void gemm_nt(const float* __restrict__ A, const float* __restrict__ Bm, float* __restrict__ C,
             int lda, int ldb, int ldc,
             ll sAb, ll sAh, ll sBb, ll sBh, ll sCb, ll sCh,
             float alpha)
{
  __shared__ float As[64][65];
  __shared__ float Bs[64][65];
  int z = blockIdx.z; int b = z >> 3; int h = z & 7;
  A  += (ll)b*sAb + (ll)h*sAh;
  Bm += (ll)b*sBb + (ll)h*sBh;
  C  += (ll)b*sCb + (ll)h*sCh;
  int n0 = blockIdx.x*64, m0 = blockIdx.y*64;
  int tid = threadIdx.x;
  int kk = tid & 63, rr = tid >> 6;
  #pragma unroll
  for (int r = 0; r < 16; r++){
    As[rr + 4*r][kk] = A [(ll)(m0 + rr + 4*r)*lda + kk];
    Bs[rr + 4*r][kk] = Bm[(ll)(n0 + rr + 4*r)*ldb + kk];
  }
  __syncthreads();
  int tx = tid & 15, ty = tid >> 4;
  float acc[4][4] = {};
  for (int k = 0; k < 64; k++){
    float a[4], bv[4];
    #pragma unroll
    for (int i = 0; i < 4; i++) a[i] = As[ty + 16*i][k];
    #pragma unroll
    for (int j = 0; j < 4; j++) bv[j] = Bs[tx + 16*j][k];
    #pragma unroll
    for (int i = 0; i < 4; i++)
      #pragma unroll
      for (int j = 0; j < 4; j++)
        acc[i][j] += a[i]*bv[j];
  }
  #pragma unroll
  for (int i = 0; i < 4; i++)
    #pragma unroll
    for (int j = 0; j < 4; j++)
      C[(ll)(m0 + ty + 16*i)*ldc + n0 + tx + 16*j] = alpha * acc[i][j];
}

// ---------------- fused flash attention (full-key version, attn1) ----------------
__global__ __launch_bounds__(256)
void flash_k(const float* __restrict__ Q, const float* __restrict__ K,
             const float* __restrict__ V, float* __restrict__ O,
             int ldq, int ldk, int ldv, int ldo, int nkeys, float alpha,
             ll sQb, ll sQh, ll sKb, ll sKh, ll sVb, ll sVh, ll sOb, ll sOh)
{
  __shared__ float qs[64][65];
  __shared__ float kv[64][65];
  __shared__ float ps[64][65];
  int z = blockIdx.z; int b = z >> 3; int h = z & 7;
  Q += (ll)b*sQb + (ll)h*sQh;
  K += (ll)b*sKb + (ll)h*sKh;
  V += (ll)b*sVb + (ll)h*sVh;
  O += (ll)b*sOb + (ll)h*sOh;
  int m0 = blockIdx.x * 64;
  int tid = threadIdx.x;
  int kk = tid & 63, rr = tid >> 6;
  #pragma unroll
  for (int r = 0; r < 16; r++)
    qs[rr + 4*r][kk] = Q[(ll)(m0 + rr + 4*r)*ldq + kk] * alpha;
  int tx = tid & 15, ty = tid >> 4;
  float o[4][4] = {};
  float mrow[4], ssum[4];
  #pragma unroll
  for (int i = 0; i < 4; i++){ mrow[i] = -1e30f; ssum[i] = 0.f; }

  for (int n0 = 0; n0 < nkeys; n0 += 64){
    __syncthreads();
    #pragma unroll
    for (int r = 0; r < 16; r++)
      kv[rr + 4*r][kk] = K[(ll)(n0 + rr + 4*r)*ldk + kk];
    __syncthreads();
    float s[4][4] = {};
    for (int d = 0; d < 64; d++){
      float a[4], bv[4];
      #pragma unroll
      for (int i = 0; i < 4; i++) a[i] = qs[ty + 16*i][d];
      #pragma unroll
      for (int j = 0; j < 4; j++) bv[j] = kv[tx + 16*j][d];
      #pragma unroll
      for (int i = 0; i < 4; i++)
        #pragma unroll
        for (int j = 0; j < 4; j++) s[i][j] += a[i]*bv[j];
    }
    #pragma unroll
    for (int i = 0; i < 4; i++){
      float cm = fmaxf(fmaxf(s[i][0], s[i][1]), fmaxf(s[i][2], s[i][3]));
      #pragma unroll
      for (int off = 1; off < 16; off <<= 1) cm = fmaxf(cm, __shfl_xor(cm, off));
      float mn = fmaxf(mrow[i], cm);
      float scale = expf(mrow[i] - mn);
      mrow[i] = mn;
      float psum = 0.f;
      #pragma unroll
      for (int j = 0; j < 4; j++){ s[i][j] = expf(s[i][j] - mn); psum += s[i][j]; }
      #pragma unroll
      for (int off = 1; off < 16; off <<= 1) psum += __shfl_xor(psum, off);
      ssum[i] = ssum[i]*scale + psum;
      #pragma unroll
      for (int j = 0; j < 4; j++){
        o[i][j] *= scale;
        ps[ty + 16*i][tx + 16*j] = s[i][j];
      }
    }
    __syncthreads();
    #pragma unroll
    for (int r = 0; r < 16; r++)
      kv[rr + 4*r][kk] = V[(ll)(n0 + rr + 4*r)*ldv + kk];
    __syncthreads();
    for (int kx = 0; kx < 64; kx++){
      float a[4], bv[4];
      #pragma unroll
      for (int i = 0; i < 4; i++) a[i] = ps[ty + 16*i][kx];
      #pragma unroll
      for (int j = 0; j < 4; j++) bv[j] = kv[kx][tx + 16*j];
      #pragma unroll
      for (int i = 0; i < 4; i++)
        #pragma unroll
        for (int j = 0; j < 4; j++) o[i][j] += a[i]*bv[j];
    }
  }
  #pragma unroll
  for (int i = 0; i < 4; i++){
    float inv = 1.f / ssum[i];
    #pragma unroll
    for (int j = 0; j < 4; j++)
      O[(ll)(m0 + ty + 16*i)*ldo + tx + 16*j] = o[i][j] * inv;
  }
}

// ---------------- attn3 split flash: partial (unnormalized o, m, l) ----------------
__global__ __launch_bounds__(256)
void flash3_part_k(const float* __restrict__ Q, const float* __restrict__ K,
                   const float* __restrict__ V,
                   float* __restrict__ po, float* __restrict__ pm, float* __restrict__ pl,
                   int ldq, int ldk, int ldv,
                   ll sQb, ll sQh, ll sKb, ll sKh, ll sVb, ll sVh)
{
  __shared__ float qs[64][65];
  __shared__ float kv[64][65];
  __shared__ float ps[64][65];
  int z = blockIdx.z; int b = z >> 3; int h = z & 7;
  int split = blockIdx.y;
  Q += (ll)b*sQb + (ll)h*sQh;
  K += (ll)b*sKb + (ll)h*sKh;
  V += (ll)b*sVb + (ll)h*sVh;
  int m0 = blockIdx.x * 64;
  int koff = split * (NTOK/NSPLIT);
  int tid = threadIdx.x;
  int kk = tid & 63, rr = tid >> 6;
  #pragma unroll
  for (int r = 0; r < 16; r++)
    qs[rr + 4*r][kk] = Q[(ll)(m0 + rr + 4*r)*ldq + kk];
  int tx = tid & 15, ty = tid >> 4;
  float o[4][4] = {};
  float mrow[4], ssum[4];
  #pragma unroll
  for (int i = 0; i < 4; i++){ mrow[i] = -1e30f; ssum[i] = 0.f; }

  for (int n0 = koff; n0 < koff + NTOK/NSPLIT; n0 += 64){
    __syncthreads();
    #pragma unroll
    for (int r = 0; r < 16; r++)
      kv[rr + 4*r][kk] = K[(ll)(n0 + rr + 4*r)*ldk + kk];
    __syncthreads();
    float s[4][4] = {};
    for (int d = 0; d < 64; d++){
      float a[4], bv[4];
      #pragma unroll
      for (int i = 0; i < 4; i++) a[i] = qs[ty + 16*i][d];
      #pragma unroll
      for (int j = 0; j < 4; j++) bv[j] = kv[tx + 16*j][d];
      #pragma unroll
      for (int i = 0; i < 4; i++)
        #pragma unroll
        for (int j = 0; j < 4; j++) s[i][j] += a[i]*bv[j];
    }
    #pragma unroll
    for (int i = 0; i < 4; i++){
      float cm = fmaxf(fmaxf(s[i][0], s[i][1]), fmaxf(s[i][2], s[i][3]));
      #pragma unroll
      for (int off = 1; off < 16; off <<= 1) cm = fmaxf(cm, __shfl_xor(cm, off));
      float mn = fmaxf(mrow[i], cm);
      float scale = expf(mrow[i] - mn);
      mrow[i] = mn;
      float psum = 0.f;
      #pragma unroll
      for (int j = 0; j < 4; j++){ s[i][j] = expf(s[i][j] - mn); psum += s[i][j]; }
      #pragma unroll
      for (int off = 1; off < 16; off <<= 1) psum += __shfl_xor(psum, off);
      ssum[i] = ssum[i]*scale + psum;
      #pragma unroll
      for (int j = 0; j < 4; j++){
        o[i][j] *= scale;
        ps[ty + 16*i][tx + 16*j] = s[i][j];
      }
    }
    __syncthreads();
    #pragma unroll
    for (int r = 0; r < 16; r++)
      kv[rr + 4*r][kk] = V[(ll)(n0 + rr + 4*r)*ldv + kk];
    __syncthreads();
    for (int kx = 0; kx < 64; kx++){
      float a[4], bv[4];
      #pragma unroll
      for (int i = 0; i < 4; i++) a[i] = ps[ty + 16*i][kx];
      #pragma unroll
      for (int j = 0; j < 4; j++) bv[j] = kv[kx][tx + 16*j];
      #pragma unroll
      for (int i = 0; i < 4; i++)
        #pragma unroll
        for (int j = 0; j < 4; j++) o[i][j] += a[i]*bv[j];
    }
  }
  int bs = z*NSPLIT + split;
  #pragma unroll
  for (int i = 0; i < 4; i++){
    int row = m0 + ty + 16*i;
    #pragma unroll
    for (int j = 0; j < 4; j++)
      po[((ll)bs*NLAND + row)*64 + tx + 16*j] = o[i][j];
    if (tx == 0){
      pm[(ll)bs*NLAND + row] = mrow[i];
      pl[(ll)bs*NLAND + row] = ssum[i];
    }
  }
}

// combine splits -> av[bh][row][64]
__global__ __launch_bounds__(256)
void flash3_comb_k(const float* __restrict__ po, const float* __restrict__ pm,
                   const float* __restrict__ pl, float* __restrict__ av){
  int bh = blockIdx.y;
  int row = blockIdx.x*4 + (threadIdx.x >> 6);
  int col = threadIdx.x & 63;
  float ms = -1e30f;
  float mv[NSPLIT];
  #pragma unroll
  for (int s = 0; s < NSPLIT; s++){
    mv[s] = pm[((ll)bh*NSPLIT + s)*NLAND + row];
    ms = fmaxf(ms, mv[s]);
  }
  float osum = 0.f, lsum = 0.f;
  #pragma unroll
  for (int s = 0; s < NSPLIT; s++){
    float w = expf(mv[s] - ms);
    osum += w * po[(((ll)bh*NSPLIT + s)*NLAND + row)*64 + col];
    lsum += w * pl[((ll)bh*NSPLIT + s)*NLAND + row];
  }
  av[((ll)bh*NLAND + row)*64 + col] = osum / lsum;
}

// ---------------- row softmax (a2) ----------------
__global__ __launch_bounds__(256) void softmax_rows_k(float* __restrict__ data, int cols){
  __shared__ float red[256];
  float* row = data + (ll)blockIdx.x * cols;
  int tid = threadIdx.x;
  float m = -1e30f;
  for (int c = tid; c < cols; c += 256) m = fmaxf(m, row[c]);
  m = bred(red, m, tid, 1);
  float s = 0.f;
  for (int c = tid; c < cols; c += 256){ float e = expf(row[c] - m); row[c] = e; s += e; }
  s = bred(red, s, tid, 0);
  float inv = 1.f/s;
  for (int c = tid; c < cols; c += 256) row[c] *= inv;
}

// ---------------- landmark means ----------------
__global__ __launch_bounds__(256) void landmarks_k(const float* __restrict__ qkv,
                                                   float* __restrict__ ql, float* __restrict__ kl){
  int idx = blockIdx.x*256 + threadIdx.x;
  int d = idx & 63;
  int i = (idx >> 6) & 255;
  int h = (idx >> 14) & 7;
  int b = idx >> 17;
  const float* base = qkv + ((ll)b*NTOK + (ll)i*16)*1536 + h*64 + d;
  float sq = 0.f, sk = 0.f;
  #pragma unroll
  for (int l = 0; l < 16; l++){ sq += base[l*1536]; sk += base[l*1536 + 512]; }
  ql[idx] = sq * (0.125f/16.f);
  kl[idx] = sk * (1.f/16.f);
}

// ---------------- pinv scaling ----------------
__global__ void init_scal_k(unsigned* s){ s[0] = 0u; s[1] = 0u; }

__global__ __launch_bounds__(256) void a2_maxsums_k(const float* __restrict__ a2, unsigned* __restrict__ gm){
  __shared__ float red[256];
  const float* A = a2 + (ll)blockIdx.x*65536;
  int tid = threadIdx.x;
  float cs = 0.f, rs = 0.f;
  for (int i = 0; i < 256; i++) cs += A[i*256 + tid];
  for (int j = 0; j < 256; j++) rs += A[tid*256 + j];
  float cmax = bred(red, cs, tid, 1);
  float rmax = bred(red, rs, tid, 1);
  if (tid == 0){
    atomicMax(gm + 0, __float_as_uint(rmax));
    atomicMax(gm + 1, __float_as_uint(cmax));
  }
}

__global__ __launch_bounds__(256) void zinit_k(const float* __restrict__ a2, float* __restrict__ z,
                                               const unsigned* __restrict__ gm){
  float inv = 1.f / (__uint_as_float(gm[0]) * __uint_as_float(gm[1]));
  int idx = blockIdx.x*256 + threadIdx.x;
  int j = idx & 255, i = (idx >> 8) & 255, bh = idx >> 16;
  z[idx] = a2[(ll)bh*65536 + j*256 + i] * inv;
}

// ---------------- depthwise conv ----------------
__global__ __launch_bounds__(256) void dwconv_add_k(const float* __restrict__ qkv,
                                                    const float* __restrict__ cw, float* __restrict__ out){
  __shared__ float sv[160][64];
  __shared__ float w[KCONV];
  int z = blockIdx.y; int b = z >> 3; int h = z & 7;
  int t0 = blockIdx.x * 128;
  int tid = threadIdx.x;
  if (tid < KCONV) w[tid] = cw[h*KCONV + tid];
  const float* vbase = qkv + (ll)b*NTOK*1536 + 1024 + h*64;
  for (int e = tid; e < 160*64; e += 256){
    int r = e >> 6, d = e & 63;
    int t = t0 - 16 + r;
    sv[r][d] = (t >= 0 && t < NTOK) ? vbase[(ll)t*1536 + d] : 0.f;
  }
  __syncthreads();
  float* obase = out + (ll)b*NTOK*512 + h*64;
  for (int e = tid; e < 128*64; e += 256){
    int r = e >> 6, d = e & 63;
    float s = 0.f;
    #pragma unroll
    for (int kk = 0; kk < KCONV; kk++) s += sv[r+kk][d]*w[kk];
    obase[(ll)(t0+r)*512 + d] += s;
  }
}

// ---------------- final head ----------------
__global__ __launch_bounds__(256) void head_k(const float* __restrict__ hb, const float* __restrict__ fns,
      const float* __restrict__ fnb, const float* __restrict__ fw, const float* __restrict__ fb,
      float* __restrict__ out){
  __shared__ float red[256];
  int b = blockIdx.x;
  const float* xr = hb + (ll)b*NTOK*DMODEL;
  int tid = threadIdx.x;
  float v0 = xr[tid], v1 = xr[tid+256];
  float mu = bred(red, v0+v1, tid, 0) * (1.f/512.f);
  float d0 = v0-mu, d1 = v1-mu;
  float var = bred(red, d0*d0 + d1*d1, tid, 0) * (1.f/512.f);
  float inv = 1.f/sqrtf(var + 1e-5f);
  float y0 = d0*inv*fns[tid]     + fnb[tid];
  float y1 = d1*inv*fns[tid+256] + fnb[tid+256];
  float dot = bred(red, y0*fw[tid] + y1*fw[tid+256], tid, 0);
  if (tid == 0){
    float logit = dot + fb[0];
    float prob = 1.f/(1.f + expf(-logit));
    out[b] = logit; out[4+b] = prob; out[8+b] = (prob > 0.5f) ? 1.f : 0.f;
  }
}

// =============================================================================
extern "C" void kernel_launch(void* const* d_in, const int* in_sizes, int n_in,
                              void* d_out, int out_size, void* d_ws, size_t ws_size,
                              hipStream_t stream)
{
  (void)in_sizes; (void)n_in; (void)out_size;
  const float* data  = (const float*)d_in[0];
  const float* fc1_w = (const float*)d_in[1];
  const float* fc1_b = (const float*)d_in[2];
  const float* cls   = (const float*)d_in[3];
  const float* ln_s  = (const float*)d_in[4];
  const float* ln_b  = (const float*)d_in[5];
  const float* qkv_w = (const float*)d_in[6];
  const float* out_w = (const float*)d_in[7];
  const float* out_b = (const float*)d_in[8];
  const float* convw = (const float*)d_in[9];
  const float* fns   = (const float*)d_in[10];
  const float* fnb   = (const float*)d_in[11];
  const float* fcw   = (const float*)d_in[12];
  const float* fcb   = (const float*)d_in[13];
  float* out = (float*)d_out;
  float* ws  = (float*)d_ws;

  // workspace layout (floats) -- identical footprint to the passing round
  float* h   = ws;                   //  8,388,608
  float* x   = h   + 8388608;        //  8,388,608
  float* qkv = x   + 8388608;        // 25,165,824
  float* ql  = qkv + 25165824;       //    524,288
  float* kl  = ql  + 524288;         //    524,288
  float* a2  = kl  + 524288;         //  2,097,152
  float* zA  = a2  + 2097152;        //  2,097,152
  float* zB  = zA  + 2097152;        //  2,097,152
  float* t1  = zB  + 2097152;        //  2,097,152
  float* t2  = t1  + 2097152;        //  2,097,152
  float* t3  = t2  + 2097152;        //  2,097,152
  float* av  = t3  + 2097152;        //    524,288
  float* y2  = av  + 524288;         //    524,288
  unsigned* scal = (unsigned*)(y2 + 524288);
  float* pe = t1;                    // alias (dead before pinv)
  float* po = t1;                    // alias: 4,194,304 = t1+t2 (dead after pinv)
  float* pm = t3;                    // alias: 65,536
  float* pl = t3 + 65536;            // alias: 65,536

  const size_t NEED = (size_t)(56623104 + 16) * sizeof(float);
  if (ws_size < NEED) return;

  pe_table_k<<<(TSEQ*DMODEL + 255)/256, 256, 0, stream>>>(pe);
  // fc1: h[b,1+t] = relu(data @ fc1_w + b)
  mgemm<128,128><<<dim3(4, 128, 1), 256, 0, stream>>>(
      data, fc1_w, h, nullptr, fc1_b,
      NBATCH*TSEQ, INDIM, INDIM, DMODEL, DMODEL,
      0, 0, 0, 0.f, 0.f, 1|2|16);
  pe_cls_add_k<<<(NBATCH*NTOK*DMODEL)/256, 256, 0, stream>>>(h, cls, pe);

  for (int L = 0; L < 2; L++){
    const float* qw = qkv_w + (ll)L*DMODEL*1536;
    const float* ow = out_w + (ll)L*DMODEL*DMODEL;
    const float* ob = out_b + (ll)L*DMODEL;
    const float* cw = convw + (ll)L*NHEAD*KCONV;

    ln_rows_k<<<NBATCH*NTOK, 256, 0, stream>>>(h, x, ln_s + L*DMODEL, ln_b + L*DMODEL);
    // qkv = x @ qkv_w
    mgemm<128,128><<<dim3(12, 128, 1), 256, 0, stream>>>(
        x, qw, qkv, nullptr, nullptr,
        NBATCH*NTOK, DMODEL, DMODEL, 1536, 1536,
        0, 0, 0, 0.f, 0.f, 0);
    landmarks_k<<<2048, 256, 0, stream>>>(qkv, ql, kl);

    // attn2 = softmax(ql @ kl^T)  (fp32 path, feeds pinv scaling)
    gemm_nt<<<dim3(4, 4, NBH), 256, 0, stream>>>(
        ql, kl, a2, 64, 64, 256,
        131072, 16384, 131072, 16384, 524288, 65536, 1.f);
    softmax_rows_k<<<NBH*NLAND, 256, 0, stream>>>(a2, 256);

    init_scal_k<<<1, 1, 0, stream>>>(scal);
    a2_maxsums_k<<<NBH, 256, 0, stream>>>(a2, scal);
    zinit_k<<<8192, 256, 0, stream>>>(a2, zA, scal);

    // Newton-Schulz x6 (bf16 MFMA, fp32 out)
    float* zc = zA; float* zn = zB;
    for (int it = 0; it < 6; it++){
      mgemm<64,64><<<dim3(4, 4, NBH), 256, 0, stream>>>(      // t1 = a2@z
          a2, zc, t1, nullptr, nullptr, 256, 256, 256, 256, 256,
          65536, 65536, 65536, 0.f, 0.f, 0);
      mgemm<64,64><<<dim3(4, 4, NBH), 256, 0, stream>>>(      // t2 = 7t1 - t1@t1
          t1, t1, t2, t1, nullptr, 256, 256, 256, 256, 256,
          65536, 65536, 65536, 7.f, -1.f, 4);
      mgemm<64,64><<<dim3(4, 4, NBH), 256, 0, stream>>>(      // t3 = 15t1 - t1@t2
          t1, t2, t3, t1, nullptr, 256, 256, 256, 256, 256,
          65536, 65536, 65536, 15.f, -1.f, 4);
      mgemm<64,64><<<dim3(4, 4, NBH), 256, 0, stream>>>(      // zn = 3.25z - 0.25 z@t3
          zc, t3, zn, zc, nullptr, 256, 256, 256, 256, 256,
          65536, 65536, 65536, 3.25f, -0.25f, 4);
      float* tmp = zc; zc = zn; zn = tmp;
    }

    // av = softmax(ql @ k^T) @ v  -- 8-way key-split flash + combine
    flash3_part_k<<<dim3(4, NSPLIT, NBH), 256, 0, stream>>>(
        ql, qkv + 512, qkv + 1024, po, pm, pl,
        64, 1536, 1536,
        131072, 16384, (ll)NTOK*1536, 64, (ll)NTOK*1536, 64);
    flash3_comb_k<<<dim3(64, NBH), 256, 0, stream>>>(po, pm, pl, av);

    // y2 = pinv @ av
    mgemm<64,64><<<dim3(1, 4, NBH), 256, 0, stream>>>(
        zc, av, y2, nullptr, nullptr, 256, 256, 256, 64, 64,
        65536, 16384, 16384, 0.f, 0.f, 0);

    // x = softmax(0.125 q @ kl^T) @ y2  (fused flash)
    flash_k<<<dim3(64, 1, NBH), 256, 0, stream>>>(
        qkv, kl, y2, x,
        1536, 64, 64, 512, NLAND, 0.125f,
        (ll)NTOK*1536, 64, 131072, 16384, 131072, 16384, (ll)NTOK*512, 64);

    // x += depthwise_conv(v)
    dwconv_add_k<<<dim3(32, NBH), 256, 0, stream>>>(qkv, cw, x);

    // h = h + x @ out_w + out_b
    mgemm<128,128><<<dim3(4, 128, 1), 256, 0, stream>>>(
        x, ow, h, nullptr, ob,
        NBATCH*NTOK, DMODEL, DMODEL, DMODEL, DMODEL,
        0, 0, 0, 0.f, 0.f, 1|8);
  }

  head_k<<<4, 256, 0, stream>>>(h, fns, fnb, fcw, fcb, out);
}